// Round 5
// baseline (184.787 us; speedup 1.0000x reference)
//
#include <hip/hip_runtime.h>

#define B_ROWS 16384
#define S_ROWS 12800
#define DIM    128

static constexpr float SCL = 20.609929155556617f;  // log2(e) / 0.07

typedef __attribute__((ext_vector_type(8))) short short8;
typedef __attribute__((ext_vector_type(4))) float f32x4;

// f32 -> bf16 round-to-nearest-even
__device__ __forceinline__ unsigned short f2bf(float f) {
  unsigned int u = __float_as_uint(f);
  unsigned int r = (u + 0x7FFFu + ((u >> 16) & 1u)) >> 16;
  return (unsigned short)r;
}

// Sortable packing: larger float -> larger key; ties -> smaller col wins (matches jnp.argmax).
__device__ __forceinline__ unsigned long long packMax(float v, int col) {
  unsigned int b = __float_as_uint(v);
  unsigned int key = (b & 0x80000000u) ? ~b : (b | 0x80000000u);
  return ((unsigned long long)key << 32) | (unsigned long long)(0xFFFFFFFFu - (unsigned int)col);
}

// async global->LDS, 16B per lane, wave-uniform LDS base (HW adds lane*16)
__device__ __forceinline__ void gld16(const unsigned short* g, unsigned short* l) {
  __builtin_amdgcn_global_load_lds(
      (const __attribute__((address_space(1))) unsigned int*)g,
      (__attribute__((address_space(3))) unsigned int*)l,
      16, 0, 0);
}

// normalize + bf16-ify centroids; blocks 3200.. also zero the accumulators
__global__ __launch_bounds__(256) void prep(const float* __restrict__ cent,
                                            unsigned short* __restrict__ cbf_u,
                                            unsigned short* __restrict__ cbf_s,
                                            float* __restrict__ centsum,
                                            unsigned long long* __restrict__ gpacked,
                                            float* __restrict__ jsum) {
  int bid = blockIdx.x;
  if (bid >= 3200) {  // 64 init blocks
    int i = (bid - 3200) * 256 + threadIdx.x;
    if (i < S_ROWS) centsum[i] = 0.f;
    if (i < B_ROWS) gpacked[i] = 0ull;
    if (i == 0) jsum[0] = 0.f;
    return;
  }
  int row  = bid * 4 + (threadIdx.x >> 6);
  int lane = threadIdx.x & 63;
  float2 v = ((const float2*)(cent + (size_t)row * DIM))[lane];
  float ss = v.x * v.x + v.y * v.y;
  #pragma unroll
  for (int m = 32; m; m >>= 1) ss += __shfl_xor(ss, m, 64);
  float inv = 1.0f / fmaxf(sqrtf(ss), 1e-12f);
  float cx = v.x * inv, cy = v.y * inv;
  ((unsigned int*)(cbf_u + (size_t)row * DIM))[lane] =
      (unsigned int)f2bf(cx) | ((unsigned int)f2bf(cy) << 16);
  ((unsigned int*)(cbf_s + (size_t)row * DIM))[lane] =
      (unsigned int)f2bf(cx * SCL) | ((unsigned int)f2bf(cy * SCL) << 16);
}

// issue one 128x128 bf16 tile's 8 global_load_lds for this wave (rows [w*32, w*32+32))
__device__ __forceinline__ void stage_tile(const unsigned short* __restrict__ src, int base,
                                           int w, int lane, unsigned short* dst) {
  #pragma unroll
  for (int i = 0; i < 8; ++i) {
    int rb = w * 32 + i * 4;
    int r  = rb + (lane >> 4);
    int ch = (lane & 15) ^ (r & 7);
    gld16(src + (size_t)(base + r) * DIM + ch * 8, dst + rb * 128);
  }
}

// Strip GEMM: block = 128 rows x NT tiles of 128 cols, K=128 resident in registers.
// 4 waves; wave tile = 128 rows x 32 cols (waves own DISJOINT B columns ->
// 8 ds_read_b128 per wave per tile, no duplication). A = a[8][4] (128 VGPR).
// MODE 0: A=cbf_s, B=cbf_u; centsum[row] += sum_cols exp2(acc)   NT=20, CH=5
// MODE 1: A=features(f32->bf16), B=cbf_s; running max/argmax      NT=25, CH=4
template <int MODE>
__global__ __launch_bounds__(256, 2) void strip_mfma(const float* __restrict__ features,
                                                     const unsigned short* __restrict__ cbf_u,
                                                     const unsigned short* __restrict__ cbf_s,
                                                     float* __restrict__ centsum,
                                                     unsigned long long* __restrict__ gpacked) {
  constexpr int NT = (MODE == 0) ? 20 : 25;
  __shared__ unsigned short Bs[2][128 * 128];  // 64 KB

  const int row0  = blockIdx.y * 128;
  const int tile0 = blockIdx.x * NT;
  const unsigned short* Bsrc = (MODE == 0) ? cbf_u : cbf_s;

  const int t    = threadIdx.x;
  const int w    = t >> 6;
  const int lane = t & 63;
  const int lg = lane >> 4, li = lane & 15;

  // ---- prologue: A tile into Bs[0], then A fragments -> registers ----
  if (MODE == 0) {
    stage_tile(cbf_s, row0, w, lane, Bs[0]);
    asm volatile("s_waitcnt vmcnt(0)" ::: "memory");
    __syncthreads();
  } else {
    #pragma unroll
    for (int i = 0; i < 8; ++i) {
      int q = i * 256 + t;
      int r = q >> 4, c = q & 15;
      const float* src = features + (size_t)(row0 + r) * DIM + c * 8;
      float4 v0 = *(const float4*)src;
      float4 v1 = *(const float4*)(src + 4);
      short8 h;
      h[0] = (short)f2bf(v0.x); h[1] = (short)f2bf(v0.y);
      h[2] = (short)f2bf(v0.z); h[3] = (short)f2bf(v0.w);
      h[4] = (short)f2bf(v1.x); h[5] = (short)f2bf(v1.y);
      h[6] = (short)f2bf(v1.z); h[7] = (short)f2bf(v1.w);
      *(short8*)&Bs[0][r * 128 + (c ^ (r & 7)) * 8] = h;
    }
    __syncthreads();
  }

  short8 a[8][4];  // all 128 rows x K=128 for this wave (128 VGPR)
  #pragma unroll
  for (int m = 0; m < 8; ++m)
    #pragma unroll
    for (int ks = 0; ks < 4; ++ks) {
      int r  = m * 16 + li;
      int ch = (ks * 4 + lg) ^ (r & 7);
      a[m][ks] = *(const short8*)&Bs[0][r * 128 + ch * 8];
    }
  __syncthreads();  // all A reads done before Bs[0] is reused for B tiles

  // ---- running epilogue state ----
  float rs[8][4];            // MODE 0: row-sum partials (this wave's col slice)
  float bv[8][4];            // MODE 1: best value
  unsigned int bcode[8];     // MODE 1: byte j of bcode[m] = tt*2+n for (m,j)
  #pragma unroll
  for (int m = 0; m < 8; ++m) {
    bcode[m] = 0u;
    #pragma unroll
    for (int j = 0; j < 4; ++j) { rs[m][j] = 0.f; bv[m][j] = -3.0e38f; }
  }
  const f32x4 zero4 = {0.f, 0.f, 0.f, 0.f};

  // ---- pre-stage B tile 0 ----
  stage_tile(Bsrc, tile0 * 128, w, lane, Bs[0]);
  __syncthreads();

  // ---- main strip loop: prefetch(t+1) || compute(t) ----
  for (int tt = 0; tt < NT; ++tt) {
    if (tt + 1 < NT)
      stage_tile(Bsrc, (tile0 + tt + 1) * 128, w, lane, Bs[(tt + 1) & 1]);
    const unsigned short* cur = Bs[tt & 1];

    f32x4 acc[8][2];
    #pragma unroll
    for (int ks = 0; ks < 4; ++ks) {
      short8 b[2];
      #pragma unroll
      for (int n = 0; n < 2; ++n) {
        int c  = w * 32 + n * 16 + li;
        int ch = (ks * 4 + lg) ^ (c & 7);
        b[n] = *(const short8*)&cur[c * 128 + ch * 8];
      }
      #pragma unroll
      for (int m = 0; m < 8; ++m)
        #pragma unroll
        for (int n = 0; n < 2; ++n)
          acc[m][n] = __builtin_amdgcn_mfma_f32_16x16x32_bf16(
              a[m][ks], b[n], (ks == 0) ? zero4 : acc[m][n], 0, 0, 0);
    }

    // per-tile running epilogue (C/D: col = li, row = lg*4 + j)
    if (MODE == 0) {
      #pragma unroll
      for (int m = 0; m < 8; ++m)
        #pragma unroll
        for (int n = 0; n < 2; ++n)
          #pragma unroll
          for (int j = 0; j < 4; ++j)
            rs[m][j] += exp2f(acc[m][n][j]);
    } else {
      #pragma unroll
      for (int m = 0; m < 8; ++m)
        #pragma unroll
        for (int j = 0; j < 4; ++j)
          #pragma unroll
          for (int n = 0; n < 2; ++n) {
            float v = acc[m][n][j];
            if (v > bv[m][j]) {   // strict >: earliest (smallest col) wins
              bv[m][j] = v;
              bcode[m] = (bcode[m] & ~(0xFFu << (8 * j))) |
                         ((unsigned int)(tt * 2 + n) << (8 * j));
            }
          }
    }
    __syncthreads();  // prefetch landed (vmcnt0 drain) + all waves done with `cur`
  }

  // ---- strip-end reduction + one atomic per row per wave ----
  if (MODE == 0) {
    #pragma unroll
    for (int m = 0; m < 8; ++m)
      #pragma unroll
      for (int j = 0; j < 4; ++j) {
        float s = rs[m][j];
        #pragma unroll
        for (int msk = 1; msk < 16; msk <<= 1) s += __shfl_xor(s, msk, 64);
        if (li == 0) atomicAdd(&centsum[row0 + m * 16 + lg * 4 + j], s);
      }
  } else {
    #pragma unroll
    for (int m = 0; m < 8; ++m)
      #pragma unroll
      for (int j = 0; j < 4; ++j) {
        float v = bv[m][j];
        unsigned int code = (bcode[m] >> (8 * j)) & 0xFFu;
        int c = (tile0 + (int)(code >> 1)) * 128 + w * 32 + (int)(code & 1) * 16 + li;
        #pragma unroll
        for (int msk = 1; msk < 16; msk <<= 1) {
          float ov = __shfl_xor(v, msk, 64);
          int   oc = __shfl_xor(c, msk, 64);
          if (ov > v || (ov == v && oc < c)) { v = ov; c = oc; }
        }
        if (li == 0) atomicMax(&gpacked[row0 + m * 16 + lg * 4 + j], packMax(v, c));
      }
  }
}

__global__ __launch_bounds__(256) void finalize_rows(const unsigned long long* __restrict__ gpacked,
                                                     const float* __restrict__ centsum,
                                                     float* __restrict__ jsum) {
  __shared__ float sdata[4];
  int b = blockIdx.x * 256 + threadIdx.x;
  unsigned long long pk = gpacked[b];
  unsigned int key = (unsigned int)(pk >> 32);
  unsigned int col = 0xFFFFFFFFu - (unsigned int)(pk & 0xFFFFFFFFu);
  unsigned int bits = (key & 0x80000000u) ? (key & 0x7FFFFFFFu) : ~key;
  float msc = __uint_as_float(bits);       // max dot * log2(e)/T
  float p = exp2f(msc);                    // = exp(max dot / T)
  float J = logf(p) - logf(p + centsum[col]);  // BALANCE = 1.0
  #pragma unroll
  for (int msk = 1; msk < 64; msk <<= 1) J += __shfl_xor(J, msk, 64);
  int lane = threadIdx.x & 63, wv = threadIdx.x >> 6;
  if (lane == 0) sdata[wv] = J;
  __syncthreads();
  if (threadIdx.x == 0) atomicAdd(jsum, sdata[0] + sdata[1] + sdata[2] + sdata[3]);
}

__global__ void write_out(const float* __restrict__ jsum, float* __restrict__ out) {
  out[0] = -(jsum[0] / (float)B_ROWS);
}

extern "C" void kernel_launch(void* const* d_in, const int* in_sizes, int n_in,
                              void* d_out, int out_size, void* d_ws, size_t ws_size,
                              hipStream_t stream) {
  const float* features  = (const float*)d_in[0];
  const float* centroids = (const float*)d_in[1];
  float* out = (float*)d_out;

  // ws: cbf_u[S*D] u16 | cbf_s[S*D] u16 | centsum[S] f32 | gpacked[B] u64 | jsum f32 (~6.74 MB)
  unsigned short* cbf_u = (unsigned short*)d_ws;
  unsigned short* cbf_s = cbf_u + (size_t)S_ROWS * DIM;
  float* centsum = (float*)(cbf_s + (size_t)S_ROWS * DIM);
  unsigned long long* gpacked = (unsigned long long*)(centsum + S_ROWS);
  float* jsum = (float*)(gpacked + B_ROWS);

  prep<<<dim3(3264), dim3(256), 0, stream>>>(centroids, cbf_u, cbf_s, centsum, gpacked, jsum);
  // MODE0: 100 row-blocks x 5 col-chunks (NT=20) = 500 blocks (~2/CU)
  strip_mfma<0><<<dim3(5, S_ROWS / 128), dim3(256), 0, stream>>>(features, cbf_u, cbf_s, centsum, gpacked);
  // MODE1: 128 row-blocks x 4 col-chunks (NT=25) = 512 blocks (2/CU)
  strip_mfma<1><<<dim3(4, B_ROWS / 128), dim3(256), 0, stream>>>(features, cbf_u, cbf_s, centsum, gpacked);
  finalize_rows<<<dim3(B_ROWS / 256), dim3(256), 0, stream>>>(gpacked, centsum, jsum);
  write_out<<<dim3(1), dim3(1), 0, stream>>>(jsum, out);
}

// Round 6
// 181.477 us; speedup vs baseline: 1.0182x; 1.0182x over previous
//
#include <hip/hip_runtime.h>

#define B_ROWS 16384
#define S_ROWS 12800
#define DIM    128
#define NTILES 25          // 64-col tiles per strip
#define NCHUNK 8           // col chunks: 8 * 25 * 64 = 12800
#define TILE_U16 (64 * 128)  // one B buffer: 64 cols x 128 K bf16 = 16 KB

static constexpr float SCL = 20.609929155556617f;  // log2(e) / 0.07

typedef __attribute__((ext_vector_type(8))) short short8;
typedef __attribute__((ext_vector_type(4))) float f32x4;

// f32 -> bf16 round-to-nearest-even
__device__ __forceinline__ unsigned short f2bf(float f) {
  unsigned int u = __float_as_uint(f);
  unsigned int r = (u + 0x7FFFu + ((u >> 16) & 1u)) >> 16;
  return (unsigned short)r;
}

// Sortable packing: larger float -> larger key; ties -> smaller col wins (matches jnp.argmax).
__device__ __forceinline__ unsigned long long packMax(float v, int col) {
  unsigned int b = __float_as_uint(v);
  unsigned int key = (b & 0x80000000u) ? ~b : (b | 0x80000000u);
  return ((unsigned long long)key << 32) | (unsigned long long)(0xFFFFFFFFu - (unsigned int)col);
}

// async global->LDS, 16B per lane, wave-uniform LDS base (HW adds lane*16)
__device__ __forceinline__ void gld16(const unsigned short* g, unsigned short* l) {
  __builtin_amdgcn_global_load_lds(
      (const __attribute__((address_space(1))) unsigned int*)g,
      (__attribute__((address_space(3))) unsigned int*)l,
      16, 0, 0);
}

// normalize + bf16-ify centroids; blocks 3200.. also zero the accumulators
__global__ __launch_bounds__(256) void prep(const float* __restrict__ cent,
                                            unsigned short* __restrict__ cbf_u,
                                            unsigned short* __restrict__ cbf_s,
                                            float* __restrict__ centsum,
                                            unsigned long long* __restrict__ gpacked,
                                            float* __restrict__ jsum) {
  int bid = blockIdx.x;
  if (bid >= 3200) {  // 64 init blocks
    int i = (bid - 3200) * 256 + threadIdx.x;
    if (i < S_ROWS) centsum[i] = 0.f;
    if (i < B_ROWS) gpacked[i] = 0ull;
    if (i == 0) jsum[0] = 0.f;
    return;
  }
  int row  = bid * 4 + (threadIdx.x >> 6);
  int lane = threadIdx.x & 63;
  float2 v = ((const float2*)(cent + (size_t)row * DIM))[lane];
  float ss = v.x * v.x + v.y * v.y;
  #pragma unroll
  for (int m = 32; m; m >>= 1) ss += __shfl_xor(ss, m, 64);
  float inv = 1.0f / fmaxf(sqrtf(ss), 1e-12f);
  float cx = v.x * inv, cy = v.y * inv;
  ((unsigned int*)(cbf_u + (size_t)row * DIM))[lane] =
      (unsigned int)f2bf(cx) | ((unsigned int)f2bf(cy) << 16);
  ((unsigned int*)(cbf_s + (size_t)row * DIM))[lane] =
      (unsigned int)f2bf(cx * SCL) | ((unsigned int)f2bf(cy * SCL) << 16);
}

// stage one 64-row x 128-K bf16 tile (16 KB); wave w stages rows [w*16, w*16+16)
__device__ __forceinline__ void stage64(const unsigned short* __restrict__ src, int colbase,
                                        int w, int lane, unsigned short* dst) {
  #pragma unroll
  for (int i = 0; i < 4; ++i) {
    int rb = w * 16 + i * 4;
    int r  = rb + (lane >> 4);
    int ch = (lane & 15) ^ (r & 7);
    gld16(src + (size_t)(colbase + r) * DIM + ch * 8, dst + rb * 128);
  }
}

// Strip GEMM: block = 128 rows x 25 tiles of 64 cols; K=128; A resident in registers.
// 4 waves, wave tile 64x32 (wr=w>>1 row half, wc=w&1 col half). 3 B-buffers, depth-2
// prefetch, counted vmcnt(4) at loop top, raw s_barrier (no vmcnt(0) in loop).
// MODE 0: A=cbf_s, B=cbf_u; centsum[row] += sum_cols exp2(acc)
// MODE 1: A=features(f32->bf16), B=cbf_s; running max/argmax over cols
template <int MODE>
__global__ __launch_bounds__(256, 3) void strip_mfma(const float* __restrict__ features,
                                                     const unsigned short* __restrict__ cbf_u,
                                                     const unsigned short* __restrict__ cbf_s,
                                                     float* __restrict__ centsum,
                                                     unsigned long long* __restrict__ gpacked) {
  __shared__ unsigned short lds[3 * TILE_U16];  // 48 KB; prologue A uses [0, 32 KB)

  const int row0  = blockIdx.y * 128;
  const int tile0 = blockIdx.x * NTILES;
  const unsigned short* Bsrc = (MODE == 0) ? cbf_u : cbf_s;

  const int t    = threadIdx.x;
  const int w    = t >> 6;
  const int lane = t & 63;
  const int wr = w >> 1, wc = w & 1;
  const int lg = lane >> 4, li = lane & 15;

  // ---- prologue: A tile (128x128) into lds[0..32KB), swizzled ----
  if (MODE == 0) {
    #pragma unroll
    for (int i = 0; i < 8; ++i) {
      int rb = w * 32 + i * 4;
      int r  = rb + (lane >> 4);
      int ch = (lane & 15) ^ (r & 7);
      gld16(cbf_s + (size_t)(row0 + r) * DIM + ch * 8, &lds[rb * 128]);
    }
    asm volatile("s_waitcnt vmcnt(0)" ::: "memory");
    __syncthreads();
  } else {
    #pragma unroll
    for (int i = 0; i < 8; ++i) {
      int q = i * 256 + t;
      int r = q >> 4, c = q & 15;
      const float* src = features + (size_t)(row0 + r) * DIM + c * 8;
      float4 v0 = *(const float4*)src;
      float4 v1 = *(const float4*)(src + 4);
      short8 h;
      h[0] = (short)f2bf(v0.x); h[1] = (short)f2bf(v0.y);
      h[2] = (short)f2bf(v0.z); h[3] = (short)f2bf(v0.w);
      h[4] = (short)f2bf(v1.x); h[5] = (short)f2bf(v1.y);
      h[6] = (short)f2bf(v1.z); h[7] = (short)f2bf(v1.w);
      *(short8*)&lds[r * 128 + (c ^ (r & 7)) * 8] = h;
    }
    __syncthreads();
  }

  short8 a[4][4];  // this wave's 64 rows x K=128 (64 VGPR)
  #pragma unroll
  for (int m = 0; m < 4; ++m)
    #pragma unroll
    for (int ks = 0; ks < 4; ++ks) {
      int r  = wr * 64 + m * 16 + li;
      int ch = (ks * 4 + lg) ^ (r & 7);
      a[m][ks] = *(const short8*)&lds[r * 128 + ch * 8];
    }
  __syncthreads();  // all A reads done before lds is reused for B tiles

  // ---- running epilogue state ----
  float rs[4][4];            // MODE 0: row-sum partials (this wave's 32-col slice)
  float bv[4][4];            // MODE 1: best value
  unsigned int bcode[4];     // MODE 1: byte j of bcode[m] = tt*2+n
  #pragma unroll
  for (int m = 0; m < 4; ++m) {
    bcode[m] = 0u;
    #pragma unroll
    for (int j = 0; j < 4; ++j) { rs[m][j] = 0.f; bv[m][j] = -3.0e38f; }
  }
  const f32x4 zero4 = {0.f, 0.f, 0.f, 0.f};

  // ---- pre-stage tiles 0,1 (8 loads/wave outstanding) ----
  unsigned short* b0 = lds;                 // rotating buffer pointers (regs only)
  unsigned short* b1 = lds + TILE_U16;
  unsigned short* b2 = lds + 2 * TILE_U16;
  stage64(Bsrc, tile0 * 64, w, lane, b0);
  stage64(Bsrc, (tile0 + 1) * 64, w, lane, b1);

  // ---- main loop: vmcnt(4) counted wait; never drain to 0 until the last tile ----
  for (int tt = 0; tt < NTILES; ++tt) {
    if (tt == NTILES - 1) { asm volatile("s_waitcnt vmcnt(0)" ::: "memory"); }
    else                  { asm volatile("s_waitcnt vmcnt(4)" ::: "memory"); }
    __builtin_amdgcn_s_barrier();           // tile tt fully in LDS; buffer b2 provably free
    if (tt + 2 < NTILES)
      stage64(Bsrc, (tile0 + tt + 2) * 64, w, lane, b2);

    const unsigned short* cur = b0;

    f32x4 acc[4][2];
    #pragma unroll
    for (int ks = 0; ks < 4; ++ks) {
      short8 b[2];
      #pragma unroll
      for (int n = 0; n < 2; ++n) {
        int c  = wc * 32 + n * 16 + li;     // local B row (output col) 0..63
        int ch = (ks * 4 + lg) ^ (c & 7);
        b[n] = *(const short8*)&cur[c * 128 + ch * 8];
      }
      #pragma unroll
      for (int m = 0; m < 4; ++m)
        #pragma unroll
        for (int n = 0; n < 2; ++n)
          acc[m][n] = __builtin_amdgcn_mfma_f32_16x16x32_bf16(
              a[m][ks], b[n], (ks == 0) ? zero4 : acc[m][n], 0, 0, 0);
    }

    // per-tile running epilogue (C/D: col = li, row = lg*4 + j)
    if (MODE == 0) {
      #pragma unroll
      for (int m = 0; m < 4; ++m)
        #pragma unroll
        for (int n = 0; n < 2; ++n)
          #pragma unroll
          for (int j = 0; j < 4; ++j)
            rs[m][j] += exp2f(acc[m][n][j]);
    } else {
      #pragma unroll
      for (int m = 0; m < 4; ++m)
        #pragma unroll
        for (int j = 0; j < 4; ++j)
          #pragma unroll
          for (int n = 0; n < 2; ++n) {
            float v = acc[m][n][j];
            if (v > bv[m][j]) {   // strict >: earliest (smallest col) wins
              bv[m][j] = v;
              bcode[m] = (bcode[m] & ~(0xFFu << (8 * j))) |
                         ((unsigned int)(tt * 2 + n) << (8 * j));
            }
          }
    }

    unsigned short* tmp = b0; b0 = b1; b1 = b2; b2 = tmp;  // rotate buffers
  }

  // ---- strip-end reduction + one atomic per row per wave ----
  if (MODE == 0) {
    #pragma unroll
    for (int m = 0; m < 4; ++m)
      #pragma unroll
      for (int j = 0; j < 4; ++j) {
        float s = rs[m][j];
        #pragma unroll
        for (int msk = 1; msk < 16; msk <<= 1) s += __shfl_xor(s, msk, 64);
        if (li == 0) atomicAdd(&centsum[row0 + wr * 64 + m * 16 + lg * 4 + j], s);
      }
  } else {
    #pragma unroll
    for (int m = 0; m < 4; ++m)
      #pragma unroll
      for (int j = 0; j < 4; ++j) {
        float v = bv[m][j];
        unsigned int code = (bcode[m] >> (8 * j)) & 0xFFu;
        int c = (tile0 + (int)(code >> 1)) * 64 + wc * 32 + (int)(code & 1) * 16 + li;
        #pragma unroll
        for (int msk = 1; msk < 16; msk <<= 1) {
          float ov = __shfl_xor(v, msk, 64);
          int   oc = __shfl_xor(c, msk, 64);
          if (ov > v || (ov == v && oc < c)) { v = ov; c = oc; }
        }
        if (li == 0) atomicMax(&gpacked[row0 + wr * 64 + m * 16 + lg * 4 + j], packMax(v, c));
      }
  }
}

__global__ __launch_bounds__(256) void finalize_rows(const unsigned long long* __restrict__ gpacked,
                                                     const float* __restrict__ centsum,
                                                     float* __restrict__ jsum) {
  __shared__ float sdata[4];
  int b = blockIdx.x * 256 + threadIdx.x;
  unsigned long long pk = gpacked[b];
  unsigned int key = (unsigned int)(pk >> 32);
  unsigned int col = 0xFFFFFFFFu - (unsigned int)(pk & 0xFFFFFFFFu);
  unsigned int bits = (key & 0x80000000u) ? (key & 0x7FFFFFFFu) : ~key;
  float msc = __uint_as_float(bits);       // max dot * log2(e)/T
  float p = exp2f(msc);                    // = exp(max dot / T)
  float J = logf(p) - logf(p + centsum[col]);  // BALANCE = 1.0
  #pragma unroll
  for (int msk = 1; msk < 64; msk <<= 1) J += __shfl_xor(J, msk, 64);
  int lane = threadIdx.x & 63, wv = threadIdx.x >> 6;
  if (lane == 0) sdata[wv] = J;
  __syncthreads();
  if (threadIdx.x == 0) atomicAdd(jsum, sdata[0] + sdata[1] + sdata[2] + sdata[3]);
}

__global__ void write_out(const float* __restrict__ jsum, float* __restrict__ out) {
  out[0] = -(jsum[0] / (float)B_ROWS);
}

extern "C" void kernel_launch(void* const* d_in, const int* in_sizes, int n_in,
                              void* d_out, int out_size, void* d_ws, size_t ws_size,
                              hipStream_t stream) {
  const float* features  = (const float*)d_in[0];
  const float* centroids = (const float*)d_in[1];
  float* out = (float*)d_out;

  // ws: cbf_u[S*D] u16 | cbf_s[S*D] u16 | centsum[S] f32 | gpacked[B] u64 | jsum f32 (~6.74 MB)
  unsigned short* cbf_u = (unsigned short*)d_ws;
  unsigned short* cbf_s = cbf_u + (size_t)S_ROWS * DIM;
  float* centsum = (float*)(cbf_s + (size_t)S_ROWS * DIM);
  unsigned long long* gpacked = (unsigned long long*)(centsum + S_ROWS);
  float* jsum = (float*)(gpacked + B_ROWS);

  prep<<<dim3(3264), dim3(256), 0, stream>>>(centroids, cbf_u, cbf_s, centsum, gpacked, jsum);
  // MODE0: 100 row-blocks x 8 col-chunks = 800 blocks (~3/CU)
  strip_mfma<0><<<dim3(NCHUNK, S_ROWS / 128), dim3(256), 0, stream>>>(features, cbf_u, cbf_s, centsum, gpacked);
  // MODE1: 128 row-blocks x 8 col-chunks = 1024 blocks
  strip_mfma<1><<<dim3(NCHUNK, B_ROWS / 128), dim3(256), 0, stream>>>(features, cbf_u, cbf_s, centsum, gpacked);
  finalize_rows<<<dim3(B_ROWS / 256), dim3(256), 0, stream>>>(gpacked, centsum, jsum);
  write_out<<<dim3(1), dim3(1), 0, stream>>>(jsum, out);
}

// Round 7
// 117.752 us; speedup vs baseline: 1.5693x; 1.5412x over previous
//
#include <hip/hip_runtime.h>

#define B_ROWS 16384
#define S_ROWS 12800
#define DIM    128
#define NBLK   100          // S_ROWS / 128

static constexpr float SCL = 20.609929155556617f;  // log2(e) / 0.07

typedef __attribute__((ext_vector_type(8))) short short8;
typedef __attribute__((ext_vector_type(4))) float f32x4;

// f32 -> bf16 round-to-nearest-even
__device__ __forceinline__ unsigned short f2bf(float f) {
  unsigned int u = __float_as_uint(f);
  unsigned int r = (u + 0x7FFFu + ((u >> 16) & 1u)) >> 16;
  return (unsigned short)r;
}

// Sortable packing: larger float -> larger key; ties -> smaller col wins (matches jnp.argmax).
__device__ __forceinline__ unsigned long long packMax(float v, int col) {
  unsigned int b = __float_as_uint(v);
  unsigned int key = (b & 0x80000000u) ? ~b : (b | 0x80000000u);
  return ((unsigned long long)key << 32) | (unsigned long long)(0xFFFFFFFFu - (unsigned int)col);
}

// async global->LDS, 16B per lane, wave-uniform LDS base (HW adds lane*16)
__device__ __forceinline__ void gld16(const unsigned short* g, unsigned short* l) {
  __builtin_amdgcn_global_load_lds(
      (const __attribute__((address_space(1))) unsigned int*)g,
      (__attribute__((address_space(3))) unsigned int*)l,
      16, 0, 0);
}

// normalize + bf16-ify centroids; blocks 3200.. also zero the accumulators
__global__ __launch_bounds__(256) void prep(const float* __restrict__ cent,
                                            unsigned short* __restrict__ cbf_u,
                                            unsigned short* __restrict__ cbf_s,
                                            float* __restrict__ centsum,
                                            unsigned long long* __restrict__ gpacked,
                                            float* __restrict__ jsum) {
  int bid = blockIdx.x;
  if (bid >= 3200) {  // 64 init blocks
    int i = (bid - 3200) * 256 + threadIdx.x;
    if (i < S_ROWS) centsum[i] = 0.f;
    if (i < B_ROWS) gpacked[i] = 0ull;
    if (i == 0) jsum[0] = 0.f;
    return;
  }
  int row  = bid * 4 + (threadIdx.x >> 6);
  int lane = threadIdx.x & 63;
  float2 v = ((const float2*)(cent + (size_t)row * DIM))[lane];
  float ss = v.x * v.x + v.y * v.y;
  #pragma unroll
  for (int m = 32; m; m >>= 1) ss += __shfl_xor(ss, m, 64);
  float inv = 1.0f / fmaxf(sqrtf(ss), 1e-12f);
  float cx = v.x * inv, cy = v.y * inv;
  ((unsigned int*)(cbf_u + (size_t)row * DIM))[lane] =
      (unsigned int)f2bf(cx) | ((unsigned int)f2bf(cy) << 16);
  ((unsigned int*)(cbf_s + (size_t)row * DIM))[lane] =
      (unsigned int)f2bf(cx * SCL) | ((unsigned int)f2bf(cy * SCL) << 16);
}

// stage one 128-row x 128-K bf16 tile (32 KB); wave w stages rows [w*32, w*32+32)
__device__ __forceinline__ void stage_tile(const unsigned short* __restrict__ src, int base,
                                           int w, int lane, unsigned short* dst) {
  #pragma unroll
  for (int i = 0; i < 8; ++i) {
    int rb = w * 32 + i * 4;
    int r  = rb + (lane >> 4);
    int ch = (lane & 15) ^ (r & 7);
    gld16(src + (size_t)(base + r) * DIM + ch * 8, dst + rb * 128);
  }
}

// ---- MODE 0 (symmetric): block (chunk c, strip bi) computes col tiles k in
// [start,end) of the cyclic upper fold: bj = (bi+k) % 100, k=0..50 (k=50 only
// for bi<50). Off-diagonal tiles contribute BOTH rowsums (-> centsum[rows],
// running rs) and colsums (-> centsum[cols], flushed per tile). Diagonal (k=0)
// contributes rowsums only. A=cbf_s (scaled), B=cbf_u; exp2 epilogue.
__global__ __launch_bounds__(256, 2) void sym_mfma(const unsigned short* __restrict__ cbf_u,
                                                   const unsigned short* __restrict__ cbf_s,
                                                   float* __restrict__ centsum) {
  __shared__ unsigned short Bs[2][128 * 128];  // 64 KB

  const int bi   = blockIdx.y;          // strip 0..99
  const int c    = blockIdx.x;          // chunk 0..4
  const int row0 = bi * 128;
  int start = (c == 0) ? 0 : (1 + 10 * c);   // chunk0: k=0..10 (11), else 10 each
  int end   = 11 + 10 * c;
  if (bi >= 50 && end > 50) end = 50;        // k=50 owned by bi<50 only
  const int nt = end - start;

  const int t    = threadIdx.x;
  const int w    = t >> 6;
  const int lane = t & 63;
  const int wr = w >> 1, wc = w & 1;
  const int lg = lane >> 4, li = lane & 15;

  // ---- prologue: A tile (rows, scaled) into Bs[0]; fragments -> registers ----
  stage_tile(cbf_s, row0, w, lane, Bs[0]);
  asm volatile("s_waitcnt vmcnt(0)" ::: "memory");
  __syncthreads();

  short8 a[4][4];
  #pragma unroll
  for (int m = 0; m < 4; ++m)
    #pragma unroll
    for (int ks = 0; ks < 4; ++ks) {
      int r  = wr * 64 + m * 16 + li;
      int ch = (ks * 4 + lg) ^ (r & 7);
      a[m][ks] = *(const short8*)&Bs[0][r * 128 + ch * 8];
    }
  __syncthreads();  // A reads done before Bs[0] is reused

  float rs[4][4];
  #pragma unroll
  for (int m = 0; m < 4; ++m)
    #pragma unroll
    for (int j = 0; j < 4; ++j) rs[m][j] = 0.f;
  const f32x4 zero4 = {0.f, 0.f, 0.f, 0.f};

  // ---- pre-stage first B tile ----
  unsigned short* pb0 = Bs[0];
  unsigned short* pb1 = Bs[1];
  {
    int bj = bi + start; if (bj >= NBLK) bj -= NBLK;
    stage_tile(cbf_u, bj * 128, w, lane, pb0);
  }
  __syncthreads();

  for (int ii = 0; ii < nt; ++ii) {
    const int k = start + ii;
    if (ii + 1 < nt) {
      int bj2 = bi + k + 1; if (bj2 >= NBLK) bj2 -= NBLK;
      stage_tile(cbf_u, bj2 * 128, w, lane, pb1);
    }
    int bj = bi + k; if (bj >= NBLK) bj -= NBLK;
    const int colbase = bj * 128;
    const unsigned short* cur = pb0;

    f32x4 acc[4][4];
    #pragma unroll
    for (int ks = 0; ks < 4; ++ks) {
      short8 b[4];
      #pragma unroll
      for (int n = 0; n < 4; ++n) {
        int cc = wc * 64 + n * 16 + li;
        int ch = (ks * 4 + lg) ^ (cc & 7);
        b[n] = *(const short8*)&cur[cc * 128 + ch * 8];
      }
      #pragma unroll
      for (int m = 0; m < 4; ++m)
        #pragma unroll
        for (int n = 0; n < 4; ++n)
          acc[m][n] = __builtin_amdgcn_mfma_f32_16x16x32_bf16(
              a[m][ks], b[n], (ks == 0) ? zero4 : acc[m][n], 0, 0, 0);
    }

    // epilogue: e feeds rowsums (running) and colsums (flushed this tile)
    float cs[4] = {0.f, 0.f, 0.f, 0.f};
    #pragma unroll
    for (int m = 0; m < 4; ++m)
      #pragma unroll
      for (int n = 0; n < 4; ++n)
        #pragma unroll
        for (int j = 0; j < 4; ++j) {
          float e = exp2f(acc[m][n][j]);
          rs[m][j] += e;
          cs[n] += e;
        }
    if (k != 0) {  // mirror contribution: centsum[col] += colsum (uniform branch)
      #pragma unroll
      for (int n = 0; n < 4; ++n) {
        cs[n] += __shfl_xor(cs[n], 16, 64);
        cs[n] += __shfl_xor(cs[n], 32, 64);
      }
      if (lg == 0) {
        #pragma unroll
        for (int n = 0; n < 4; ++n)
          atomicAdd(&centsum[colbase + wc * 64 + n * 16 + li], cs[n]);
      }
    }
    __syncthreads();  // prefetch landed + all waves done with cur
    unsigned short* tmp = pb0; pb0 = pb1; pb1 = tmp;
  }

  // ---- strip-end rowsum reduction ----
  #pragma unroll
  for (int m = 0; m < 4; ++m)
    #pragma unroll
    for (int j = 0; j < 4; ++j) {
      float s = rs[m][j];
      #pragma unroll
      for (int msk = 1; msk < 16; msk <<= 1) s += __shfl_xor(s, msk, 64);
      if (li == 0) atomicAdd(&centsum[row0 + wr * 64 + m * 16 + lg * 4 + j], s);
    }
}

// ---- MODE 1: R2-exact argmax strip (A=features f32->bf16, B=cbf_s scaled) ----
__global__ __launch_bounds__(256, 2) void argmax_mfma(const float* __restrict__ features,
                                                      const unsigned short* __restrict__ cbf_s,
                                                      unsigned long long* __restrict__ gpacked) {
  constexpr int NT = 25;
  __shared__ unsigned short Bs[2][128 * 128];  // 64 KB

  const int row0  = blockIdx.y * 128;
  const int tile0 = blockIdx.x * NT;

  const int t    = threadIdx.x;
  const int w    = t >> 6;
  const int lane = t & 63;
  const int wr = w >> 1, wc = w & 1;
  const int lg = lane >> 4, li = lane & 15;

  // prologue: features f32 -> bf16, swizzled LDS write, then A frags -> regs
  #pragma unroll
  for (int i = 0; i < 8; ++i) {
    int q = i * 256 + t;
    int r = q >> 4, c = q & 15;
    const float* src = features + (size_t)(row0 + r) * DIM + c * 8;
    float4 v0 = *(const float4*)src;
    float4 v1 = *(const float4*)(src + 4);
    short8 h;
    h[0] = (short)f2bf(v0.x); h[1] = (short)f2bf(v0.y);
    h[2] = (short)f2bf(v0.z); h[3] = (short)f2bf(v0.w);
    h[4] = (short)f2bf(v1.x); h[5] = (short)f2bf(v1.y);
    h[6] = (short)f2bf(v1.z); h[7] = (short)f2bf(v1.w);
    *(short8*)&Bs[0][r * 128 + (c ^ (r & 7)) * 8] = h;
  }
  __syncthreads();

  short8 a[4][4];
  #pragma unroll
  for (int m = 0; m < 4; ++m)
    #pragma unroll
    for (int ks = 0; ks < 4; ++ks) {
      int r  = wr * 64 + m * 16 + li;
      int ch = (ks * 4 + lg) ^ (r & 7);
      a[m][ks] = *(const short8*)&Bs[0][r * 128 + ch * 8];
    }
  __syncthreads();

  float bv[4][4];
  int   bc[4][4];
  #pragma unroll
  for (int m = 0; m < 4; ++m)
    #pragma unroll
    for (int j = 0; j < 4; ++j) { bv[m][j] = -3.0e38f; bc[m][j] = 0; }
  const f32x4 zero4 = {0.f, 0.f, 0.f, 0.f};

  stage_tile(cbf_s, tile0 * 128, w, lane, Bs[0]);
  __syncthreads();

  for (int tt = 0; tt < NT; ++tt) {
    if (tt + 1 < NT)
      stage_tile(cbf_s, (tile0 + tt + 1) * 128, w, lane, Bs[(tt + 1) & 1]);
    const unsigned short* cur = Bs[tt & 1];

    f32x4 acc[4][4];
    #pragma unroll
    for (int ks = 0; ks < 4; ++ks) {
      short8 b[4];
      #pragma unroll
      for (int n = 0; n < 4; ++n) {
        int cc = wc * 64 + n * 16 + li;
        int ch = (ks * 4 + lg) ^ (cc & 7);
        b[n] = *(const short8*)&cur[cc * 128 + ch * 8];
      }
      #pragma unroll
      for (int m = 0; m < 4; ++m)
        #pragma unroll
        for (int n = 0; n < 4; ++n)
          acc[m][n] = __builtin_amdgcn_mfma_f32_16x16x32_bf16(
              a[m][ks], b[n], (ks == 0) ? zero4 : acc[m][n], 0, 0, 0);
    }

    const int cbase = (tile0 + tt) * 128 + wc * 64 + li;
    #pragma unroll
    for (int m = 0; m < 4; ++m)
      #pragma unroll
      for (int j = 0; j < 4; ++j)
        #pragma unroll
        for (int n = 0; n < 4; ++n) {
          float v = acc[m][n][j];
          if (v > bv[m][j]) { bv[m][j] = v; bc[m][j] = cbase + n * 16; }  // strict >: smallest col wins
        }
    __syncthreads();
  }

  #pragma unroll
  for (int m = 0; m < 4; ++m)
    #pragma unroll
    for (int j = 0; j < 4; ++j) {
      float v = bv[m][j];
      int   c = bc[m][j];
      #pragma unroll
      for (int msk = 1; msk < 16; msk <<= 1) {
        float ov = __shfl_xor(v, msk, 64);
        int   oc = __shfl_xor(c, msk, 64);
        if (ov > v || (ov == v && oc < c)) { v = ov; c = oc; }
      }
      if (li == 0) atomicMax(&gpacked[row0 + wr * 64 + m * 16 + lg * 4 + j], packMax(v, c));
    }
}

__global__ __launch_bounds__(256) void finalize_rows(const unsigned long long* __restrict__ gpacked,
                                                     const float* __restrict__ centsum,
                                                     float* __restrict__ jsum) {
  __shared__ float sdata[4];
  int b = blockIdx.x * 256 + threadIdx.x;
  unsigned long long pk = gpacked[b];
  unsigned int key = (unsigned int)(pk >> 32);
  unsigned int col = 0xFFFFFFFFu - (unsigned int)(pk & 0xFFFFFFFFu);
  unsigned int bits = (key & 0x80000000u) ? (key & 0x7FFFFFFFu) : ~key;
  float msc = __uint_as_float(bits);       // max dot * log2(e)/T
  float p = exp2f(msc);                    // = exp(max dot / T)
  float J = logf(p) - logf(p + centsum[col]);  // BALANCE = 1.0
  #pragma unroll
  for (int msk = 1; msk < 64; msk <<= 1) J += __shfl_xor(J, msk, 64);
  int lane = threadIdx.x & 63, wv = threadIdx.x >> 6;
  if (lane == 0) sdata[wv] = J;
  __syncthreads();
  if (threadIdx.x == 0) atomicAdd(jsum, sdata[0] + sdata[1] + sdata[2] + sdata[3]);
}

__global__ void write_out(const float* __restrict__ jsum, float* __restrict__ out) {
  out[0] = -(jsum[0] / (float)B_ROWS);
}

extern "C" void kernel_launch(void* const* d_in, const int* in_sizes, int n_in,
                              void* d_out, int out_size, void* d_ws, size_t ws_size,
                              hipStream_t stream) {
  const float* features  = (const float*)d_in[0];
  const float* centroids = (const float*)d_in[1];
  float* out = (float*)d_out;

  // ws: cbf_u[S*D] u16 | cbf_s[S*D] u16 | centsum[S] f32 | gpacked[B] u64 | jsum f32 (~6.74 MB)
  unsigned short* cbf_u = (unsigned short*)d_ws;
  unsigned short* cbf_s = cbf_u + (size_t)S_ROWS * DIM;
  float* centsum = (float*)(cbf_s + (size_t)S_ROWS * DIM);
  unsigned long long* gpacked = (unsigned long long*)(centsum + S_ROWS);
  float* jsum = (float*)(gpacked + B_ROWS);

  prep<<<dim3(3264), dim3(256), 0, stream>>>(centroids, cbf_u, cbf_s, centsum, gpacked, jsum);
  // symmetric S x S: 5 chunks x 100 strips = 500 blocks, ~10 tiles each (5050 total, was 10000)
  sym_mfma<<<dim3(5, NBLK), dim3(256), 0, stream>>>(cbf_u, cbf_s, centsum);
  // B x S argmax: 4 chunks x 128 row-blocks = 512 blocks, 25 tiles each (R2-exact)
  argmax_mfma<<<dim3(4, B_ROWS / 128), dim3(256), 0, stream>>>(features, cbf_s, gpacked);
  finalize_rows<<<dim3(B_ROWS / 256), dim3(256), 0, stream>>>(gpacked, centsum, jsum);
  write_out<<<dim3(1), dim3(1), 0, stream>>>(jsum, out);
}